// Round 2
// 475.056 us; speedup vs baseline: 1.0129x; 1.0129x over previous
//
#include <hip/hip_runtime.h>

// GlobalLinear: per-graph mean of node/edge features, then 3 linear
// projections + bias. DN = DG = DO = 128, DE = 64.
//
// Timed-region decomposition (R5 theory, from rocprof):
//   ~308 us  harness poison fills of the 1 GB workspace (2 x 154 us,
//            6.6 TB/s writes -- visible as fillBufferAligned in top-5,
//            NOT controllable from kernel source)
//   ~150 us  agg: 512 MB compulsory reads + ~256 MB dirty-L3 writebacks
//            (poison fill leaves Infinity Cache fully dirty; our read
//            misses evict those lines) -> ~768 MB HBM, near the wall
//   ~22 us   scan kernel + ws memset + finalize + 4 launches
// R5 change (re-run; R6 bench was an infra failure, no signal):
// eliminate the third bucket. Fuse offset prefix-sum into agg (each
// block reduces <=500 L2-resident ints), write partials to unique
// slots (no memset, no atomics), equalize node/edge chunk bytes
// (NODE_SPLIT=4 -> 128 KB, EDGE_SPLIT=4 -> 128 KB). Two launches total.

#define DN 128
#define DE 64
#define DO 128
#define NODE_SPLIT 4   // blocks per graph for node aggregation (128 KB each)
#define EDGE_SPLIT 4   // blocks per graph for edge aggregation (128 KB each)

typedef float f4v __attribute__((ext_vector_type(4)));

__device__ __forceinline__ f4v nt_load(const f4v* p) {
    return __builtin_nontemporal_load(p);
}

// ---------------------------------------------------------------------------
// Kernel 1: fused segment-sum. Each block computes its own segment offset
// (parallel reduction of the L2-resident length array), streams its chunk
// with nt float4 4-deep loads, LDS tree-reduces, and stores its partial
// sum to a UNIQUE slot (no atomics, no pre-zeroed workspace).
// Node blocks: 256 thr = 32 col-lanes (f4 over 128 cols) x 8 row-lanes.
// Edge blocks: 256 thr = 16 col-lanes (f4 over  64 cols) x 16 row-lanes.
// ---------------------------------------------------------------------------
__global__ __launch_bounds__(256) void agg_kernel(
    const float* __restrict__ nodes, const float* __restrict__ edges,
    const int* __restrict__ nlen, const int* __restrict__ elen,
    float* __restrict__ nsum, float* __restrict__ esum, int G)
{
    __shared__ int ired[256];
    __shared__ f4v sm[256];
    const int b = blockIdx.x;
    const int t = threadIdx.x;

    const bool is_node = (b < G * NODE_SPLIT);
    const int gb = is_node ? b : (b - G * NODE_SPLIT);
    const int g = gb / NODE_SPLIT;       // NODE_SPLIT == EDGE_SPLIT == 4
    const int c = gb % NODE_SPLIT;
    const int* __restrict__ larr = is_node ? nlen : elen;

    // --- inline exclusive prefix: off = sum(larr[0..g)) ---
    int part = 0;
    for (int i = t; i < g; i += 256) part += larr[i];
    ired[t] = part;
    __syncthreads();
    #pragma unroll
    for (int s = 128; s >= 1; s >>= 1) {
        if (t < s) ired[t] += ired[t + s];
        __syncthreads();
    }
    const int off = ired[0];
    const int len = larr[g];

    // --- chunk bounds for this block ---
    const int chunk = (len + NODE_SPLIT - 1) / NODE_SPLIT;
    const int r0 = (c * chunk < len) ? c * chunk : len;
    const int r1 = (c * chunk + chunk < len) ? (c * chunk + chunk) : len;
    const int span = r1 - r0;

    if (is_node) {
        const int main_end = r0 + (span & ~31);   // full 32-row groups
        const int col = t & 31;        // f4 column index: 32*4 = 128 cols
        const int rl  = t >> 5;        // 8 row lanes
        const f4v* __restrict__ base = (const f4v*)nodes; // row = 32 f4

        f4v a0 = {0.f,0.f,0.f,0.f}, a1 = a0, a2 = a0, a3 = a0;
        for (int rr = r0 + rl * 4; rr < main_end; rr += 32) {
            const size_t p = (size_t)(off + rr) * (DN / 4) + col;
            a0 += nt_load(base + p);
            a1 += nt_load(base + p + (DN / 4));
            a2 += nt_load(base + p + 2 * (DN / 4));
            a3 += nt_load(base + p + 3 * (DN / 4));
        }
        for (int r = main_end + rl; r < r1; r += 8) {
            a0 += nt_load(base + (size_t)(off + r) * (DN / 4) + col);
        }
        sm[t] = (a0 + a1) + (a2 + a3);
        __syncthreads();
        #pragma unroll
        for (int s = 128; s >= 32; s >>= 1) {
            if (t < s) sm[t] += sm[t + s];
            __syncthreads();
        }
        if (t < 32) {
            f4v* dst = (f4v*)&nsum[((size_t)g * NODE_SPLIT + c) * DN];
            dst[t] = sm[t];            // unique slot: plain store
        }
    } else {
        const int main_end = r0 + (span & ~63);   // full 64-row groups
        const int col = t & 15;        // f4 column index: 16*4 = 64 cols
        const int rl  = t >> 4;        // 16 row lanes
        const f4v* __restrict__ base = (const f4v*)edges; // row = 16 f4

        f4v a0 = {0.f,0.f,0.f,0.f}, a1 = a0, a2 = a0, a3 = a0;
        for (int rr = r0 + rl * 4; rr < main_end; rr += 64) {
            const size_t p = (size_t)(off + rr) * (DE / 4) + col;
            a0 += nt_load(base + p);
            a1 += nt_load(base + p + (DE / 4));
            a2 += nt_load(base + p + 2 * (DE / 4));
            a3 += nt_load(base + p + 3 * (DE / 4));
        }
        for (int r = main_end + rl; r < r1; r += 16) {
            a0 += nt_load(base + (size_t)(off + r) * (DE / 4) + col);
        }
        sm[t] = (a0 + a1) + (a2 + a3);
        __syncthreads();
        #pragma unroll
        for (int s = 128; s >= 16; s >>= 1) {
            if (t < s) sm[t] += sm[t + s];
            __syncthreads();
        }
        if (t < 16) {
            f4v* dst = (f4v*)&esum[((size_t)g * EDGE_SPLIT + c) * DE];
            dst[t] = sm[t];            // unique slot: plain store
        }
    }
}

// ---------------------------------------------------------------------------
// Kernel 2: reduce partial slots, scale to means, then
// out[g,o] = mean_n(g)·Wn[o] + mean_e(g)·We[o] + glob[g]·Wg[o] + bias[o]
// ---------------------------------------------------------------------------
__global__ __launch_bounds__(128) void finalize_kernel(
    const float* __restrict__ nsum, const float* __restrict__ esum,
    const float* __restrict__ glob,
    const float* __restrict__ Wn, const float* __restrict__ We,
    const float* __restrict__ Wg, const float* __restrict__ bias,
    const int* __restrict__ nlen, const int* __restrict__ elen,
    float* __restrict__ out)
{
    __shared__ float sn[DN], se_[DE], sg[DN];
    const int g = blockIdx.x;
    const int o = threadIdx.x;

    const int nl = nlen[g];
    const int el = elen[g];
    const float inv_n = 1.0f / (float)((nl > 1) ? nl : 1);
    const float inv_e = 1.0f / (float)((el > 1) ? el : 1);

    float accn = 0.f;
    #pragma unroll
    for (int s = 0; s < NODE_SPLIT; ++s)
        accn += nsum[((size_t)g * NODE_SPLIT + s) * DN + o];
    sn[o] = accn * inv_n;
    sg[o] = glob[(size_t)g * DN + o];
    if (o < DE) {
        float acce = 0.f;
        #pragma unroll
        for (int s = 0; s < EDGE_SPLIT; ++s)
            acce += esum[((size_t)g * EDGE_SPLIT + s) * DE + o];
        se_[o] = acce * inv_e;
    }
    __syncthreads();

    float acc = bias[o];
    const float4* __restrict__ wn = (const float4*)(Wn + (size_t)o * DN);
    const float4* __restrict__ wg = (const float4*)(Wg + (size_t)o * DN);
    const float4* __restrict__ we = (const float4*)(We + (size_t)o * DE);
    const float4* s4n = (const float4*)sn;
    const float4* s4g = (const float4*)sg;
    const float4* s4e = (const float4*)se_;

    #pragma unroll
    for (int i = 0; i < DN / 4; ++i) {
        const float4 a = wn[i], v = s4n[i];
        acc += a.x * v.x + a.y * v.y + a.z * v.z + a.w * v.w;
    }
    #pragma unroll
    for (int i = 0; i < DN / 4; ++i) {
        const float4 a = wg[i], v = s4g[i];
        acc += a.x * v.x + a.y * v.y + a.z * v.z + a.w * v.w;
    }
    #pragma unroll
    for (int i = 0; i < DE / 4; ++i) {
        const float4 a = we[i], v = s4e[i];
        acc += a.x * v.x + a.y * v.y + a.z * v.z + a.w * v.w;
    }
    out[(size_t)g * DO + o] = acc;
}

// ---------------------------------------------------------------------------
extern "C" void kernel_launch(void* const* d_in, const int* in_sizes, int n_in,
                              void* d_out, int out_size, void* d_ws, size_t ws_size,
                              hipStream_t stream)
{
    const float* nodes = (const float*)d_in[0];
    const float* edges = (const float*)d_in[1];
    const float* glob  = (const float*)d_in[2];
    const float* Wn    = (const float*)d_in[3];
    const float* We    = (const float*)d_in[4];
    const float* Wg    = (const float*)d_in[5];
    const float* bias  = (const float*)d_in[6];
    const int*   nlen  = (const int*)d_in[7];
    const int*   elen  = (const int*)d_in[8];
    float*       out   = (float*)d_out;

    const int G = in_sizes[7];           // 500

    // workspace layout: nsum[G*NODE_SPLIT*DN] | esum[G*EDGE_SPLIT*DE]
    // Every slot is written unconditionally by exactly one block -> no
    // memset, no atomics.
    float* nsum = (float*)d_ws;
    float* esum = nsum + (size_t)G * NODE_SPLIT * DN;

    const int agg_blocks = G * (NODE_SPLIT + EDGE_SPLIT);
    agg_kernel<<<agg_blocks, 256, 0, stream>>>(nodes, edges, nlen, elen,
                                               nsum, esum, G);

    finalize_kernel<<<G, 128, 0, stream>>>(nsum, esum, glob, Wn, We, Wg, bias,
                                           nlen, elen, out);
}